// Round 4
// baseline (787.051 us; speedup 1.0000x reference)
//
#include <hip/hip_runtime.h>
#include <math.h>

// ---------------- constants ----------------
#define P1H 66
#define P1W 204
#define P1PLANE (P1H * P1W)   // 13464 floats per (b,ic) plane, zero-padded border

// ws layout (bytes):
//   p1p   : 0           .. 110,297,088   (64*32*66*204 f32)
//   c2wT  : 110,297,088 .. 110,370,816   (32*64*9 f32, [ic][oc][9])  <- OUTSIDE p1p now
//   bn2sc : 110,370,816 .. 110,371,072   (64 f32)
//   bn2sh : 110,371,072 .. 110,371,328   (64 f32)
//   p2    : 112,459,776 .. 164,888,576   (64*64*32*100 f32)
//   -- after K2, p1p region is dead; f64 tail buffers reuse it --
//   hproj : 3,276,800   .. 16,384,000    (64*100*256 f64)
//   curs  : 16,384,000  .. 22,937,600    (64*50*256 f64)
//   cur1  : 22,937,600  .. 29,491,200    (64*50*256 f64)
//   cur2  : 29,491,200  .. 32,768,000    (64*50*128 f64)

// ---------------- KW: transpose conv2 weights + precompute bn2 affine -------
__global__ __launch_bounds__(256) void kw_prep(
    const float* __restrict__ c2w, const float* __restrict__ c2b,
    const float* __restrict__ g2, const float* __restrict__ b2,
    const float* __restrict__ m2, const float* __restrict__ v2,
    float* __restrict__ c2wT, float* __restrict__ bn2sc, float* __restrict__ bn2sh) {
  int blk = blockIdx.x;
  if (blk < 72) {
    int d = blk * 256 + threadIdx.x;          // dst index, 18432 total
    int ic = d / 576, rem = d - ic * 576;
    int oc = rem / 9, t = rem - oc * 9;
    c2wT[d] = c2w[(oc * 32 + ic) * 9 + t];
  } else if (threadIdx.x < 64) {
    int o = threadIdx.x;
    double sd = (double)g2[o] / sqrt((double)v2[o] + 1e-5);
    bn2sc[o] = (float)sd;
    bn2sh[o] = (float)(((double)c2b[o] - (double)m2[o]) * sd + (double)b2[o]);
  }
}

// ---------------- K0: zero the padded border of p1p ----------------
__global__ __launch_bounds__(256) void k0_border(float* __restrict__ p1p) {
  int plane = blockIdx.x;                       // b*32+ic, 2048 planes
  float* base = p1p + (size_t)plane * P1PLANE;
  for (int i = threadIdx.x; i < 536; i += 256) {
    int r, c;
    if (i < 204)      { r = 0;            c = i; }
    else if (i < 408) { r = 65;           c = i - 204; }
    else if (i < 472) { r = i - 408 + 1;  c = 0; }
    else              { r = i - 472 + 1;  c = 201; }
    base[r * P1W + c] = 0.f;
  }
}

// ---------------- K1: conv1(3x3,SAME) + bn1 + relu + maxpool2 ----------------
__global__ __launch_bounds__(256) void k1_conv1(
    const float* __restrict__ x,  const float* __restrict__ c1w,
    const float* __restrict__ c1b, const float* __restrict__ g1,
    const float* __restrict__ b1, const float* __restrict__ m1,
    const float* __restrict__ v1, float* __restrict__ p1p) {
  __shared__ float tile[18][67];
  __shared__ float scale[32], shift[32];
  int wx = blockIdx.x, hy = blockIdx.y, b = blockIdx.z;
  int tid = threadIdx.x;
  int gy0 = hy * 16 - 1, gx0 = wx * 64 - 1;
  const float* xb = x + (size_t)b * 128 * 400;
  for (int i = tid; i < 18 * 66; i += 256) {
    int r = i / 66, c = i - r * 66;
    int gr = gy0 + r, gc = gx0 + c;
    float v = 0.f;
    if (gr >= 0 && gr < 128 && gc >= 0 && gc < 400) v = xb[gr * 400 + gc];
    tile[r][c] = v;
  }
  if (tid < 32) {
    double s = (double)g1[tid] / sqrt((double)v1[tid] + 1e-5);
    scale[tid] = (float)s;
    shift[tid] = (float)(((double)c1b[tid] - (double)m1[tid]) * s + (double)b1[tid]);
  }
  __syncthreads();
  int tx = tid & 31, ty = tid >> 5;
  int pw = wx * 32 + tx;         // pooled col < 200
  int ph = hy * 8 + ty;          // pooled row < 64
  if (pw >= 200) return;
  float in[4][4];
#pragma unroll
  for (int r = 0; r < 4; ++r)
#pragma unroll
    for (int c = 0; c < 4; ++c) in[r][c] = tile[2 * ty + r][2 * tx + c];
  for (int ch = 0; ch < 32; ++ch) {
    float s00 = 0, s01 = 0, s10 = 0, s11 = 0;
#pragma unroll
    for (int ky = 0; ky < 3; ++ky)
#pragma unroll
      for (int kx = 0; kx < 3; ++kx) {
        float w = c1w[ch * 9 + ky * 3 + kx];   // uniform -> s_load
        s00 = fmaf(w, in[ky][kx],     s00);
        s01 = fmaf(w, in[ky][kx + 1], s01);
        s10 = fmaf(w, in[ky + 1][kx],     s10);
        s11 = fmaf(w, in[ky + 1][kx + 1], s11);
      }
    float sc = scale[ch], sh = shift[ch];
    float y00 = fmaxf(fmaf(sc, s00, sh), 0.f);
    float y01 = fmaxf(fmaf(sc, s01, sh), 0.f);
    float y10 = fmaxf(fmaf(sc, s10, sh), 0.f);
    float y11 = fmaxf(fmaf(sc, s11, sh), 0.f);
    float r = fmaxf(fmaxf(y00, y01), fmaxf(y10, y11));
    p1p[((size_t)(b * 32 + ch) * P1H + (ph + 1)) * P1W + (pw + 1)] = r;
  }
}

// ---------------- K2: conv2 v3 — lane = spatial, weights on scalar pipe -----
// lane = one pre-pool output pixel (wave = 4 rows x 16 cols). Input taps are
// per-lane coalesced vector loads (VMEM pipe, 9 imm offsets off one address);
// weights are wave-uniform s_loads from L2-resident c2wT (the direct SGPR
// operand of v_fmac). acc[32] per lane, two oc-halves -> ~55 VGPR, 8 waves/SIMD.
__global__ __launch_bounds__(256, 8) void k2_conv2(
    const float* __restrict__ p1p, const float* __restrict__ c2wT,
    const float* __restrict__ bn2sc, const float* __restrict__ bn2sh,
    float* __restrict__ p2) {
  int b = blockIdx.z;
  int tile = blockIdx.x;                       // 0..51 = 4 row-tiles x 13 col-tiles
  int rt = tile / 13, ct = tile - rt * 13;
  int wave = threadIdx.x >> 6;
  int lane = threadIdx.x & 63;
  int rl = lane >> 4, cl = lane & 15;
  int r = rt * 16 + wave * 4 + rl;             // pre-pool row 0..63
  int c = ct * 16 + cl;                        // pre-pool col (valid < 200)
  const float* pb0 = p1p + (size_t)(b * 32) * P1PLANE;
  int voff = r * P1W + c;                      // tap(0,0) element offset

#pragma unroll
  for (int pass = 0; pass < 2; ++pass) {
    int ocb = pass * 32;
    float acc[32];
#pragma unroll
    for (int o = 0; o < 32; ++o) acc[o] = 0.f;
    for (int ic = 0; ic < 32; ++ic) {
      const float* ip = pb0 + (size_t)ic * P1PLANE + voff;
      float in[9];
      in[0] = ip[0];            in[1] = ip[1];            in[2] = ip[2];
      in[3] = ip[P1W];          in[4] = ip[P1W + 1];      in[5] = ip[P1W + 2];
      in[6] = ip[2 * P1W];      in[7] = ip[2 * P1W + 1];  in[8] = ip[2 * P1W + 2];
      const float* wp = c2wT + ((ic * 64) + ocb) * 9;     // uniform -> s_load run
#pragma unroll
      for (int o = 0; o < 32; ++o) {
#pragma unroll
        for (int t = 0; t < 9; ++t)
          acc[o] = fmaf(in[t], wp[o * 9 + t], acc[o]);
      }
    }
    // epilogue: bn affine + relu + 2x2 maxpool (cross-lane) + masked store
    bool leader = ((lane & 1) == 0) && ((lane & 16) == 0);
    int pr = r >> 1, pc = c >> 1;
    bool valid = leader && (pc < 100);
#pragma unroll
    for (int o = 0; o < 32; ++o) {
      int oc = ocb + o;
      float y = fmaxf(bn2sc[oc] * acc[o] + bn2sh[oc], 0.f);   // 2 uniform consts
      float a = fmaxf(y, __shfl_xor(y, 1, 64));
      float m = fmaxf(a, __shfl_xor(a, 16, 64));
      if (valid)
        p2[((size_t)(b * 64 + oc) * 32 + pr) * 100 + pc] = m;
    }
  }
}

// ---------------- K4: freq-mean (inline) + channel_proj + LayerNorm ---------
__global__ __launch_bounds__(256) void k4_meanproj_ln(
    const float* __restrict__ p2, const float* __restrict__ pw,
    const float* __restrict__ pb, const float* __restrict__ plg,
    const float* __restrict__ plb, double* __restrict__ hproj) {
  __shared__ double hmld[64][4];
  __shared__ double sbuf[4];
  int bt0 = blockIdx.x * 4;             // 4 | 100 -> same b for all 4 rows
  int b = bt0 / 100, t0 = bt0 - b * 100;
  int tid = threadIdx.x;
  {
    int cc = tid >> 2, rr = tid & 3;
    const float* pp = p2 + (size_t)(b * 64 + cc) * 3200 + t0 + rr;
    double s = 0.0;
#pragma unroll
    for (int h = 0; h < 32; ++h) s += (double)pp[h * 100];
    hmld[cc][rr] = s * (1.0 / 32.0);
  }
  __syncthreads();
  int k = tid;
  double accv[4];
  double pbk = (double)pb[k];
#pragma unroll
  for (int r = 0; r < 4; ++r) accv[r] = pbk;
#pragma unroll 4
  for (int cc = 0; cc < 64; ++cc) {
    double w = (double)pw[cc * 256 + k];
    accv[0] = fma(hmld[cc][0], w, accv[0]);
    accv[1] = fma(hmld[cc][1], w, accv[1]);
    accv[2] = fma(hmld[cc][2], w, accv[2]);
    accv[3] = fma(hmld[cc][3], w, accv[3]);
  }
  double gk = (double)plg[k], bk = (double)plb[k];
#pragma unroll
  for (int r = 0; r < 4; ++r) {
    double v = accv[r];
#pragma unroll
    for (int off = 32; off > 0; off >>= 1) v += __shfl_down(v, off, 64);
    __syncthreads();
    if ((tid & 63) == 0) sbuf[tid >> 6] = v;
    __syncthreads();
    double mean = (sbuf[0] + sbuf[1] + sbuf[2] + sbuf[3]) * (1.0 / 256.0);
    double d = accv[r] - mean;
    double vv = d * d;
#pragma unroll
    for (int off = 32; off > 0; off >>= 1) vv += __shfl_down(vv, off, 64);
    __syncthreads();
    if ((tid & 63) == 0) sbuf[tid >> 6] = vv;
    __syncthreads();
    double var = (sbuf[0] + sbuf[1] + sbuf[2] + sbuf[3]) * (1.0 / 256.0);
    double inv = 1.0 / sqrt(var + 1e-5);
    hproj[(size_t)(bt0 + r) * 256 + k] = d * inv * gk + bk;
  }
}

// ---------------- block reduction helper (256 threads) ----------------
__device__ __forceinline__ double block_reduce_sum_256(double v, double* sbuf) {
#pragma unroll
  for (int off = 32; off > 0; off >>= 1) v += __shfl_down(v, off, 64);
  int lane = threadIdx.x & 63, wid = threadIdx.x >> 6;
  __syncthreads();
  if (lane == 0) sbuf[wid] = v;
  __syncthreads();
  return sbuf[0] + sbuf[1] + sbuf[2] + sbuf[3];
}

// ---------------- K5a: interp(x2 avg) + LayerNorm ----------------
__global__ __launch_bounds__(256) void k5a_interp_ln(
    const double* __restrict__ hproj, const float* __restrict__ ing,
    const float* __restrict__ inb, double* __restrict__ curs) {
  __shared__ double sbuf[4];
  int bs = blockIdx.x;                  // b*50 + s
  int b = bs / 50, st = bs - b * 50;
  int k = threadIdx.x;
  const double* hp = hproj + (size_t)(b * 100 + 2 * st) * 256;
  double xk = 0.5 * (hp[k] + hp[256 + k]);   // src = 2s+0.5 -> avg of pair
  double mean = block_reduce_sum_256(xk, sbuf) * (1.0 / 256.0);
  double d = xk - mean;
  double var = block_reduce_sum_256(d * d, sbuf) * (1.0 / 256.0);
  double inv = 1.0 / sqrt(var + 1e-5);
  curs[(size_t)bs * 256 + k] = d * inv * (double)ing[k] + (double)inb[k];
}

// ---------------- K5b: fc1 GEMM, 8 rows/block ----------------
__global__ __launch_bounds__(256) void k5b_fc1(
    const double* __restrict__ curs, const float* __restrict__ fc1w,
    const float* __restrict__ fc1b, double* __restrict__ cur1) {
  int row0 = blockIdx.x * 8;            // 400 blocks
  int k = threadIdx.x;
  double accv[8];
  double bk = (double)fc1b[k];
#pragma unroll
  for (int r = 0; r < 8; ++r) accv[r] = bk;
  const double* ab = curs + (size_t)row0 * 256;
#pragma unroll 4
  for (int c = 0; c < 256; ++c) {
    double w = (double)fc1w[c * 256 + k];
#pragma unroll
    for (int r = 0; r < 8; ++r)
      accv[r] = fma(ab[(size_t)r * 256 + c], w, accv[r]);   // uniform s_load
  }
#pragma unroll
  for (int r = 0; r < 8; ++r) cur1[(size_t)(row0 + r) * 256 + k] = accv[r];
}

// ---------------- K6: LIF1 scan -> spike_record ----------------
__global__ __launch_bounds__(64) void k6_lif1(
    const double* __restrict__ cur1, const float* __restrict__ beta1p,
    const float* __restrict__ thr1p, float* __restrict__ dout) {
  int b = blockIdx.x >> 2;
  int k = ((blockIdx.x & 3) << 6) + threadIdx.x;
  double beta = (double)beta1p[0];
  beta = beta < 0.0 ? 0.0 : (beta > 1.0 ? 1.0 : beta);
  double thr = (double)thr1p[0];
  double mem = 0.0;
  float* srec = dout + 128;             // spike_record after logits
  for (int t = 0; t < 50; ++t) {
    double c = cur1[(size_t)(b * 50 + t) * 256 + k];
    mem = beta * mem + c - ((mem > thr) ? thr : 0.0);   // reset uses prev mem
    srec[(size_t)(b * 50 + t) * 256 + k] = (mem > thr) ? 1.0f : 0.0f;
  }
}

// ---------------- K7: fc2 GEMM on spikes, 8 rows/block ----------------
__global__ __launch_bounds__(128) void k7_fc2(
    const float* __restrict__ dout, const float* __restrict__ fc2w,
    const float* __restrict__ fc2b, double* __restrict__ cur2) {
  int row0 = blockIdx.x * 8;            // 400 blocks
  int j = threadIdx.x;
  const float* srec = dout + 128;
  double accv[8];
  double bj = (double)fc2b[j];
#pragma unroll
  for (int r = 0; r < 8; ++r) accv[r] = bj;
#pragma unroll 4
  for (int c = 0; c < 256; ++c) {
    double w = (double)fc2w[c * 128 + j];
#pragma unroll
    for (int r = 0; r < 8; ++r)
      accv[r] = fma((double)srec[(size_t)(row0 + r) * 256 + c], w, accv[r]);  // uniform s_load
  }
#pragma unroll
  for (int r = 0; r < 8; ++r) cur2[(size_t)(row0 + r) * 128 + j] = accv[r];
}

// ---------------- K8: fused LIF2 scan + fc_out + LIF3 + logits ----------
__global__ __launch_bounds__(128) void k8_tail(
    const double* __restrict__ cur2, const float* __restrict__ fcow,
    const float* __restrict__ fcob, const float* __restrict__ beta2p,
    const float* __restrict__ thr2p, const float* __restrict__ beta3p,
    const float* __restrict__ thr3p, float* __restrict__ dout) {
  __shared__ float s2s[50][128];
  __shared__ double c3s[50][2];
  int b = blockIdx.x, j = threadIdx.x;
  double beta2 = (double)beta2p[0];
  beta2 = beta2 < 0.0 ? 0.0 : (beta2 > 1.0 ? 1.0 : beta2);
  double thr2 = (double)thr2p[0];
  double m2 = 0.0;
  for (int t = 0; t < 50; ++t) {
    double c2 = cur2[(size_t)(b * 50 + t) * 128 + j];
    m2 = beta2 * m2 + c2 - ((m2 > thr2) ? thr2 : 0.0);
    s2s[t][j] = (m2 > thr2) ? 1.0f : 0.0f;
  }
  __syncthreads();
  int t = j;
  if (t < 50) {
    double c30 = (double)fcob[0], c31 = (double)fcob[1];
#pragma unroll 4
    for (int jj = 0; jj < 128; ++jj) {
      double s = (double)s2s[t][jj];
      c30 = fma(s, (double)fcow[jj * 2 + 0], c30);
      c31 = fma(s, (double)fcow[jj * 2 + 1], c31);
    }
    c3s[t][0] = c30; c3s[t][1] = c31;
  }
  __syncthreads();
  if (j == 0) {
    double beta3 = (double)beta3p[0];
    beta3 = beta3 < 0.0 ? 0.0 : (beta3 > 1.0 ? 1.0 : beta3);
    double thr3 = (double)thr3p[0];
    double mo0 = 0.0, mo1 = 0.0, l0 = 0.0, l1 = 0.0;
    for (int tt = 0; tt < 50; ++tt) {
      mo0 = beta3 * mo0 + c3s[tt][0] - ((mo0 > thr3) ? thr3 : 0.0);
      mo1 = beta3 * mo1 + c3s[tt][1] - ((mo1 > thr3) ? thr3 : 0.0);
      l0 += mo0; l1 += mo1;
    }
    dout[b * 2 + 0] = (float)l0; dout[b * 2 + 1] = (float)l1;
  }
}

// ---------------- launch ----------------
extern "C" void kernel_launch(void* const* d_in, const int* in_sizes, int n_in,
                              void* d_out, int out_size, void* d_ws, size_t ws_size,
                              hipStream_t stream) {
  const float* x    = (const float*)d_in[0];
  const float* c1w  = (const float*)d_in[1];
  const float* c1b  = (const float*)d_in[2];
  const float* bn1g = (const float*)d_in[3];
  const float* bn1b = (const float*)d_in[4];
  const float* bn1m = (const float*)d_in[5];
  const float* bn1v = (const float*)d_in[6];
  const float* c2w  = (const float*)d_in[7];
  const float* c2b  = (const float*)d_in[8];
  const float* bn2g = (const float*)d_in[9];
  const float* bn2b = (const float*)d_in[10];
  const float* bn2m = (const float*)d_in[11];
  const float* bn2v = (const float*)d_in[12];
  const float* pw   = (const float*)d_in[13];
  const float* pb   = (const float*)d_in[14];
  const float* plg  = (const float*)d_in[15];
  const float* plb  = (const float*)d_in[16];
  const float* ing  = (const float*)d_in[17];
  const float* inb  = (const float*)d_in[18];
  const float* fc1w = (const float*)d_in[19];
  const float* fc1b = (const float*)d_in[20];
  const float* fc2w = (const float*)d_in[21];
  const float* fc2b = (const float*)d_in[22];
  const float* fcow = (const float*)d_in[23];
  const float* fcob = (const float*)d_in[24];
  const float* beta1 = (const float*)d_in[25];
  const float* thr1  = (const float*)d_in[26];
  const float* beta2 = (const float*)d_in[27];
  const float* thr2  = (const float*)d_in[28];
  const float* beta3 = (const float*)d_in[29];
  const float* thr3  = (const float*)d_in[30];

  char* ws = (char*)d_ws;
  float*  p1p   = (float*)ws;                    // 0 .. 110,297,088
  float*  c2wT  = (float*)(ws + 110297088ULL);   // strictly after p1p
  float*  bn2sc = (float*)(ws + 110370816ULL);
  float*  bn2sh = (float*)(ws + 110371072ULL);
  float*  p2    = (float*)(ws + 112459776ULL);
  double* hproj = (double*)(ws + 3276800ULL);    // tail reuses p1p (dead after k2)
  double* curs  = (double*)(ws + 16384000ULL);
  double* cur1  = (double*)(ws + 22937600ULL);
  double* cur2  = (double*)(ws + 29491200ULL);
  float* dout = (float*)d_out;

  kw_prep<<<dim3(73), 256, 0, stream>>>(c2w, c2b, bn2g, bn2b, bn2m, bn2v, c2wT, bn2sc, bn2sh);
  k0_border<<<dim3(2048), 256, 0, stream>>>(p1p);
  k1_conv1<<<dim3(7, 8, 64), 256, 0, stream>>>(x, c1w, c1b, bn1g, bn1b, bn1m, bn1v, p1p);
  k2_conv2<<<dim3(52, 1, 64), 256, 0, stream>>>(p1p, c2wT, bn2sc, bn2sh, p2);
  k4_meanproj_ln<<<dim3(1600), 256, 0, stream>>>(p2, pw, pb, plg, plb, hproj);
  k5a_interp_ln<<<dim3(3200), 256, 0, stream>>>(hproj, ing, inb, curs);
  k5b_fc1<<<dim3(400), 256, 0, stream>>>(curs, fc1w, fc1b, cur1);
  k6_lif1<<<dim3(256), 64, 0, stream>>>(cur1, beta1, thr1, dout);
  k7_fc2<<<dim3(400), 128, 0, stream>>>(dout, fc2w, fc2b, cur2);
  k8_tail<<<dim3(64), 128, 0, stream>>>(cur2, fcow, fcob, beta2, thr2, beta3, thr3, dout);
}